// Round 2
// baseline (673.267 us; speedup 1.0000x reference)
//
#include <hip/hip_runtime.h>

typedef float v2f __attribute__((ext_vector_type(2)));

#define BB 8
#define CC 3
#define HH 512
#define WW 512
#define OO 64
#define KK 9
#define HW (HH * WW)

static __device__ __forceinline__ v2f sp(float s) { v2f r; r.x = s; r.y = s; return r; }

__global__ __launch_bounds__(256, 3) void fused_deform_kernel(
    const float* __restrict__ x,
    const float* __restrict__ w_simple,
    const float* __restrict__ w_off,
    const float* __restrict__ b_off,
    const float* __restrict__ w_mask,
    const float* __restrict__ b_mask,
    float* __restrict__ out)
{
    // Weights staged to LDS, rows padded 27 -> 28 floats so dots run as 7x float4.
    __shared__ __align__(16) float s_woff[18 * 28];
    __shared__ __align__(16) float s_wmsk[9 * 28];
    __shared__ __align__(16) float s_w[64 * 28];
    __shared__ float s_boff[18];
    __shared__ float s_bmsk[9];

    const int tid = threadIdx.x;
    for (int t = tid; t < 18 * 28; t += 256) { int j = t / 28, i = t % 28; s_woff[t] = (i < 27) ? w_off[j * 27 + i] : 0.f; }
    for (int t = tid; t < 9 * 28; t += 256)  { int j = t / 28, i = t % 28; s_wmsk[t] = (i < 27) ? w_mask[j * 27 + i] : 0.f; }
    for (int t = tid; t < 64 * 28; t += 256) { int j = t / 28, i = t % 28; s_w[t]    = (i < 27) ? w_simple[j * 27 + i] : 0.f; }
    if (tid < 18) s_boff[tid] = b_off[tid];
    if (tid < 9)  s_bmsk[tid] = b_mask[tid];
    __syncthreads();

    // 2 pixels/thread: block = one full image row (256 threads x 2 = 512 cols).
    // Grid = 4096; XCD swizzle: 512 blocks (= one batch image, 3 MB) per XCD L2.
    const int bid = blockIdx.x;
    const int nbid = (bid & 7) * 512 + (bid >> 3);
    const int b = nbid >> 9;
    const int h = nbid & (HH - 1);
    const int w0 = tid;
    const int w1 = tid + 256;

    const float* xb = x + (size_t)b * CC * HW;

    // ---- 3x3 neighborhoods (zero-padded) for both pixels, packed .x/.y ----
    v2f nb[28];
    #pragma unroll
    for (int c = 0; c < CC; ++c) {
        const float* xc = xb + c * HW;
        #pragma unroll
        for (int i = 0; i < 9; ++i) {
            int yy = h - 1 + i / 3;
            float va = 0.f, vb = 0.f;
            if ((unsigned)yy < (unsigned)HH) {
                const float* row = xc + yy * WW;
                int xa = w0 - 1 + i % 3;
                int xb2 = w1 - 1 + i % 3;
                if ((unsigned)xa < (unsigned)WW) va = row[xa];
                if ((unsigned)xb2 < (unsigned)WW) vb = row[xb2];
            }
            v2f t2; t2.x = va; t2.y = vb;
            nb[c * 9 + i] = t2;
        }
    }
    nb[27] = sp(0.f);

    // ---- offset conv (18 ch), both pixels per weight read ----
    v2f offv[18];
    #pragma unroll
    for (int j = 0; j < 18; ++j) {
        v2f acc = sp(s_boff[j]);
        const float4* wp = (const float4*)(s_woff + j * 28);
        #pragma unroll
        for (int q = 0; q < 7; ++q) {
            float4 wq = wp[q];
            acc += nb[q * 4 + 0] * sp(wq.x);
            acc += nb[q * 4 + 1] * sp(wq.y);
            acc += nb[q * 4 + 2] * sp(wq.z);
            acc += nb[q * 4 + 3] * sp(wq.w);
        }
        offv[j] = acc;
    }

    // ---- mask conv (9 ch) + sigmoid ----
    v2f mval[9];
    #pragma unroll
    for (int j = 0; j < 9; ++j) {
        v2f acc = sp(s_bmsk[j]);
        const float4* wp = (const float4*)(s_wmsk + j * 28);
        #pragma unroll
        for (int q = 0; q < 7; ++q) {
            float4 wq = wp[q];
            acc += nb[q * 4 + 0] * sp(wq.x);
            acc += nb[q * 4 + 1] * sp(wq.y);
            acc += nb[q * 4 + 2] * sp(wq.z);
            acc += nb[q * 4 + 3] * sp(wq.w);
        }
        v2f m;
        m.x = __builtin_amdgcn_rcpf(1.f + __expf(-acc.x));
        m.y = __builtin_amdgcn_rcpf(1.f + __expf(-acc.y));
        mval[j] = m;
    }

    // ---- deformable bilinear sampling (branchless; valid*mask folded in weights) ----
    v2f vv[28];
    vv[27] = sp(0.f);
    #pragma unroll
    for (int k = 0; k < 9; ++k) {
        const int ki = k / 3, kj = k % 3;

        // pixel A
        float pyA = (float)(h - 1 + ki) + offv[2 * k + 0].x;
        float pxA = (float)(w0 - 1 + kj) + offv[2 * k + 1].x;
        float yA0f = floorf(pyA), xA0f = floorf(pxA);
        float tyA = pyA - yA0f, txA = pxA - xA0f;
        int yA0 = (int)yA0f, xA0 = (int)xA0f;
        int yA1 = yA0 + 1, xA1 = xA0 + 1;
        bool vyA0 = (unsigned)yA0 < (unsigned)HH, vyA1 = (unsigned)yA1 < (unsigned)HH;
        bool vxA0 = (unsigned)xA0 < (unsigned)WW, vxA1 = (unsigned)xA1 < (unsigned)WW;
        int lA00 = min(max(yA0, 0), HH - 1) * WW + min(max(xA0, 0), WW - 1);
        int lA01 = min(max(yA0, 0), HH - 1) * WW + min(max(xA1, 0), WW - 1);
        int lA10 = min(max(yA1, 0), HH - 1) * WW + min(max(xA0, 0), WW - 1);
        int lA11 = min(max(yA1, 0), HH - 1) * WW + min(max(xA1, 0), WW - 1);
        float mkA = mval[k].x;
        float wA00 = (vyA0 && vxA0) ? (1.f - tyA) * (1.f - txA) * mkA : 0.f;
        float wA01 = (vyA0 && vxA1) ? (1.f - tyA) * txA * mkA : 0.f;
        float wA10 = (vyA1 && vxA0) ? tyA * (1.f - txA) * mkA : 0.f;
        float wA11 = (vyA1 && vxA1) ? tyA * txA * mkA : 0.f;

        // pixel B
        float pyB = (float)(h - 1 + ki) + offv[2 * k + 0].y;
        float pxB = (float)(w1 - 1 + kj) + offv[2 * k + 1].y;
        float yB0f = floorf(pyB), xB0f = floorf(pxB);
        float tyB = pyB - yB0f, txB = pxB - xB0f;
        int yB0 = (int)yB0f, xB0 = (int)xB0f;
        int yB1 = yB0 + 1, xB1 = xB0 + 1;
        bool vyB0 = (unsigned)yB0 < (unsigned)HH, vyB1 = (unsigned)yB1 < (unsigned)HH;
        bool vxB0 = (unsigned)xB0 < (unsigned)WW, vxB1 = (unsigned)xB1 < (unsigned)WW;
        int lB00 = min(max(yB0, 0), HH - 1) * WW + min(max(xB0, 0), WW - 1);
        int lB01 = min(max(yB0, 0), HH - 1) * WW + min(max(xB1, 0), WW - 1);
        int lB10 = min(max(yB1, 0), HH - 1) * WW + min(max(xB0, 0), WW - 1);
        int lB11 = min(max(yB1, 0), HH - 1) * WW + min(max(xB1, 0), WW - 1);
        float mkB = mval[k].y;
        float wB00 = (vyB0 && vxB0) ? (1.f - tyB) * (1.f - txB) * mkB : 0.f;
        float wB01 = (vyB0 && vxB1) ? (1.f - tyB) * txB * mkB : 0.f;
        float wB10 = (vyB1 && vxB0) ? tyB * (1.f - txB) * mkB : 0.f;
        float wB11 = (vyB1 && vxB1) ? tyB * txB * mkB : 0.f;

        #pragma unroll
        for (int c = 0; c < CC; ++c) {
            const float* xc = xb + c * HW;
            float sA;
            sA = wA00 * xc[lA00];
            sA = fmaf(wA01, xc[lA01], sA);
            sA = fmaf(wA10, xc[lA10], sA);
            sA = fmaf(wA11, xc[lA11], sA);
            float sB;
            sB = wB00 * xc[lB00];
            sB = fmaf(wB01, xc[lB01], sB);
            sB = fmaf(wB10, xc[lB10], sB);
            sB = fmaf(wB11, xc[lB11], sB);
            v2f t2; t2.x = sA; t2.y = sB;
            vv[c * 9 + k] = t2;
        }
    }

    // ---- einsum: each LDS weight read now feeds 2 pixels ----
    const size_t obase = (size_t)b * OO * HW + (size_t)h * WW + w0;
    #pragma unroll 4
    for (int o = 0; o < OO; ++o) {
        v2f acc = sp(0.f);
        const float4* wp = (const float4*)(s_w + o * 28);
        #pragma unroll
        for (int q = 0; q < 7; ++q) {
            float4 wq = wp[q];
            acc += vv[q * 4 + 0] * sp(wq.x);
            acc += vv[q * 4 + 1] * sp(wq.y);
            acc += vv[q * 4 + 2] * sp(wq.z);
            acc += vv[q * 4 + 3] * sp(wq.w);
        }
        float* op = out + obase + (size_t)o * HW;
        __builtin_nontemporal_store(acc.x, op);
        __builtin_nontemporal_store(acc.y, op + 256);
    }
}

extern "C" void kernel_launch(void* const* d_in, const int* in_sizes, int n_in,
                              void* d_out, int out_size, void* d_ws, size_t ws_size,
                              hipStream_t stream) {
    const float* x        = (const float*)d_in[0];
    const float* w_simple = (const float*)d_in[1];
    const float* w_off    = (const float*)d_in[2];
    const float* b_off    = (const float*)d_in[3];
    const float* w_mask   = (const float*)d_in[4];
    const float* b_mask   = (const float*)d_in[5];
    float* out = (float*)d_out;

    const int grid = BB * HH;                 // 4096 blocks, one row each
    const int block = 256;
    fused_deform_kernel<<<grid, block, 0, stream>>>(x, w_simple, w_off, b_off, w_mask, b_mask, out);
}